// Round 1
// 439.337 us; speedup vs baseline: 1.0015x; 1.0015x over previous
//
#include <hip/hip_runtime.h>
#include <math.h>

#define Vv   50000
#define EMB  128
#define Hh   256
#define TKk  400
#define Bb   128
#define OOVn 10
#define N2n  512
#define VOo  50010   // V + OOV
#define NBLK 782     // (Vv + 63) / 64
#define PSTR 800     // padded partial stride

typedef __bf16 bf16x8 __attribute__((ext_vector_type(8)));
typedef float  f32x4  __attribute__((ext_vector_type(4)));

__device__ __forceinline__ float sigf(float x) { return 1.f / (1.f + __expf(-x)); }
__device__ __forceinline__ float tanh_fast(float x) {
    x = fminf(15.f, fmaxf(-15.f, x));
    float e = __expf(2.f * x);
    return (e - 1.f) / (e + 1.f);
}
__device__ __forceinline__ float wave_red(float v) {
    #pragma unroll
    for (int o = 32; o; o >>= 1) v += __shfl_down(v, o);
    return v;
}
// fp32 -> bf16 RNE
__device__ __forceinline__ unsigned short f2bf(float f) {
    unsigned u = __builtin_bit_cast(unsigned, f);
    unsigned r = u + 0x7fffu + ((u >> 16) & 1u);
    return (unsigned short)(r >> 16);
}

// ---------------------------------------------------------------------------
// K1: x[b,j] = concat(c_t_1, emb[y[b]]) . Wx[j,:] + bx[j]
// ---------------------------------------------------------------------------
__global__ __launch_bounds__(256) void k_x(
    const int* __restrict__ y, const float* __restrict__ ct1,
    const float* __restrict__ emb, const float* __restrict__ Wx,
    const float* __restrict__ bx, float* __restrict__ xw)
{
    int l = threadIdx.x & 63;
    int j = blockIdx.x * 4 + (threadIdx.x >> 6);
    int b0 = blockIdx.y * 4;
    float w[10];
    #pragma unroll
    for (int i = 0; i < 10; i++) w[i] = Wx[(size_t)j * 640 + l + 64 * i];
    float bj = bx[j];
    #pragma unroll
    for (int bi = 0; bi < 4; bi++) {
        int b = b0 + bi;
        int yy = y[b];
        float a = 0.f;
        #pragma unroll
        for (int i = 0; i < 8; i++) a += ct1[b * 512 + l + 64 * i] * w[i];
        #pragma unroll
        for (int i = 0; i < 2; i++) a += emb[(size_t)yy * 128 + l + 64 * i] * w[8 + i];
        a = wave_red(a);
        if (l == 0) xw[b * 128 + j] = a + bj;
    }
}

// ---------------------------------------------------------------------------
// K2: gates + LSTM fused
// ---------------------------------------------------------------------------
__global__ __launch_bounds__(256) void k_gates_lstm(
    const float* __restrict__ xw, const float* __restrict__ h0,
    const float* __restrict__ c0, const float* __restrict__ wih,
    const float* __restrict__ bih, const float* __restrict__ whh,
    const float* __restrict__ bhh,
    float* __restrict__ h1o, float* __restrict__ c1o)
{
    int l = threadIdx.x & 63, g = threadIdx.x >> 6;
    int n = blockIdx.x;
    int b0 = blockIdx.y * 4;
    int j = g * 256 + n;
    __shared__ float gsum[4][4];

    float wi0 = wih[(size_t)j * 128 + l];
    float wi1 = wih[(size_t)j * 128 + l + 64];
    float wh[4];
    #pragma unroll
    for (int i = 0; i < 4; i++) wh[i] = whh[(size_t)j * 256 + l + 64 * i];
    float bj = bih[j] + bhh[j];

    #pragma unroll
    for (int bi = 0; bi < 4; bi++) {
        int b = b0 + bi;
        float a = xw[b * 128 + l] * wi0 + xw[b * 128 + l + 64] * wi1;
        #pragma unroll
        for (int i = 0; i < 4; i++) a += h0[b * 256 + l + 64 * i] * wh[i];
        a = wave_red(a);
        if (l == 0) gsum[g][bi] = a + bj;
    }
    __syncthreads();
    if (threadIdx.x < 4) {
        int b = b0 + threadIdx.x;
        float ig = sigf(gsum[0][threadIdx.x]);
        float fg = sigf(gsum[1][threadIdx.x]);
        float gg = tanh_fast(gsum[2][threadIdx.x]);
        float og = sigf(gsum[3][threadIdx.x]);
        float c1 = fg * c0[b * 256 + n] + ig * gg;
        float h1 = og * tanh_fast(c1);
        h1o[b * 256 + n] = h1;
        c1o[b * 256 + n] = c1;
    }
}

// ---------------------------------------------------------------------------
// K3: dec_fea
// ---------------------------------------------------------------------------
__global__ __launch_bounds__(256) void k_dec_fea(
    const float* __restrict__ h1, const float* __restrict__ c1,
    const float* __restrict__ Wp, const float* __restrict__ bp,
    float* __restrict__ dfw)
{
    int l = threadIdx.x & 63;
    int j = blockIdx.x * 4 + (threadIdx.x >> 6);
    int b0 = blockIdx.y * 4;
    float w[8];
    #pragma unroll
    for (int i = 0; i < 8; i++) w[i] = Wp[(size_t)j * 512 + l + 64 * i];
    float bj = bp[j];
    #pragma unroll
    for (int bi = 0; bi < 4; bi++) {
        int b = b0 + bi;
        float a = 0.f;
        #pragma unroll
        for (int i = 0; i < 4; i++) a += h1[b * 256 + l + 64 * i] * w[i];
        #pragma unroll
        for (int i = 0; i < 4; i++) a += c1[b * 256 + l + 64 * i] * w[4 + i];
        a = wave_red(a);
        if (l == 0) dfw[b * 512 + j] = a + bj;
    }
}

// ---------------------------------------------------------------------------
// K4: scores
// ---------------------------------------------------------------------------
__global__ __launch_bounds__(256) void k_scores(
    const float* __restrict__ ef, const float* __restrict__ df,
    const float* __restrict__ cov, const float* __restrict__ Wc,
    const float* __restrict__ vw, float* __restrict__ sc)
{
    int w = threadIdx.x >> 6, lane = threadIdx.x & 63;
    int idx = blockIdx.x * 4 + w;
    int b = idx / TKk;
    const float* e = ef + (size_t)idx * N2n;
    const float* d = df + (size_t)b * N2n;
    float cv = cov[idx];
    float acc = 0.f;
    #pragma unroll
    for (int i = 0; i < 2; i++) {
        int n0 = lane * 4 + i * 256;
        float4 ev = *(const float4*)(e + n0);
        float4 dv = *(const float4*)(d + n0);
        float4 wc = *(const float4*)(Wc + n0);
        float4 vv = *(const float4*)(vw + n0);
        acc += tanh_fast(ev.x + dv.x + cv * wc.x) * vv.x;
        acc += tanh_fast(ev.y + dv.y + cv * wc.y) * vv.y;
        acc += tanh_fast(ev.z + dv.z + cv * wc.z) * vv.z;
        acc += tanh_fast(ev.w + dv.w + cv * wc.w) * vv.w;
    }
    acc = wave_red(acc);
    if (lane == 0) sc[idx] = acc;
}

// ---------------------------------------------------------------------------
// K5 (fused attn + ctx): grid (4, B). Each block redundantly computes the
// full-row softmax (1.6 KB read, L2-hot) and consumes its own 100-t chunk.
// s==0 block writes attn & coverage outputs. Removes k_attn launch + the
// attn global round-trip.
// ---------------------------------------------------------------------------
__global__ __launch_bounds__(512) void k_attn_ctx(
    const float* __restrict__ sc, const float* __restrict__ mask,
    const float* __restrict__ covi, const float* __restrict__ eo,
    float* __restrict__ attn, float* __restrict__ covo,
    float* __restrict__ part)
{
    int b = blockIdx.y, s = blockIdx.x;
    int tid = threadIdx.x;
    __shared__ float red[8];
    __shared__ float bc;
    __shared__ float av[100];

    float sv = (tid < TKk) ? sc[b * TKk + tid] : -3.4e38f;
    float m = sv;
    for (int off = 32; off; off >>= 1) m = fmaxf(m, __shfl_down(m, off));
    if ((tid & 63) == 0) red[tid >> 6] = m;
    __syncthreads();
    if (tid == 0) {
        float t = red[0];
        for (int i = 1; i < 8; i++) t = fmaxf(t, red[i]);
        bc = t;
    }
    __syncthreads();
    float M = bc;
    float w = (tid < TKk) ? __expf(sv - M) * mask[b * TKk + tid] : 0.f;
    float ss = wave_red(w);
    if ((tid & 63) == 0) red[tid >> 6] = ss;
    __syncthreads();
    if (tid == 0) {
        float t = 0.f;
        for (int i = 0; i < 8; i++) t += red[i];
        bc = t;
    }
    __syncthreads();
    float a = w / bc;
    if (tid < TKk) {
        if (s == 0) {
            attn[b * TKk + tid] = a;
            covo[b * TKk + tid] = covi[b * TKk + tid] + a;
        }
        int t0 = tid - s * 100;
        if (t0 >= 0 && t0 < 100) av[t0] = a;
    }
    __syncthreads();

    // ctx partial for chunk s
    int n = tid;
    const float* p = eo + ((size_t)b * TKk + s * 100) * N2n + n;
    float acc = 0.f;
    #pragma unroll 4
    for (int t = 0; t < 100; t++) acc += av[t] * p[(size_t)t * N2n];
    part[((size_t)(b * 4 + s)) * N2n + n] = acc;
}

// ---------------------------------------------------------------------------
// K6 (fused ctred + out + p_gen): rebuilds c_t in LDS from the 4 partials
// (same L2 traffic as reading cto before), computes the bf16 GEMM input.
// blockIdx.x==0 blocks additionally write cto and compute p_gen.
// ---------------------------------------------------------------------------
__global__ __launch_bounds__(256) void k_out_ctred(
    const float* __restrict__ part, const float* __restrict__ h1,
    const float* __restrict__ c1, const float* __restrict__ xw,
    const float* __restrict__ W1, const float* __restrict__ b1,
    const float* __restrict__ Wpg, const float* __restrict__ bpg,
    float* __restrict__ cto, float* __restrict__ pgo,
    unsigned short* __restrict__ abf)
{
    int l = threadIdx.x & 63;
    int j = blockIdx.x * 4 + (threadIdx.x >> 6);
    int b0 = blockIdx.y * 4;
    __shared__ float ct[4][N2n];
    __shared__ float red[4];

    for (int idx = threadIdx.x; idx < 4 * N2n; idx += 256) {
        int bi = idx >> 9, pos = idx & 511;
        size_t base = ((size_t)(b0 + bi) * 4) * N2n + pos;
        ct[bi][pos] = part[base] + part[base + N2n]
                    + part[base + 2 * N2n] + part[base + 3 * N2n];
    }
    __syncthreads();

    if (blockIdx.x == 0) {
        for (int idx = threadIdx.x; idx < 4 * N2n; idx += 256) {
            int bi = idx >> 9, pos = idx & 511;
            cto[(size_t)(b0 + bi) * N2n + pos] = ct[bi][pos];
        }
    }

    float w[12];
    #pragma unroll
    for (int i = 0; i < 12; i++) w[i] = W1[(size_t)j * 768 + l + 64 * i];
    float bj = b1[j];
    #pragma unroll
    for (int bi = 0; bi < 4; bi++) {
        int b = b0 + bi;
        float a = 0.f;
        #pragma unroll
        for (int i = 0; i < 4; i++) a += h1[b * 256 + l + 64 * i] * w[i];
        #pragma unroll
        for (int i = 0; i < 8; i++) a += ct[bi][l + 64 * i] * w[4 + i];
        a = wave_red(a);
        if (l == 0) abf[b * 256 + j] = f2bf(a + bj);
    }

    if (blockIdx.x == 0) {
        // p_gen for the 4 b's of this group
        for (int bi = 0; bi < 4; bi++) {
            int b = b0 + bi;
            float pa = 0.f;
            for (int k = threadIdx.x; k < 1152; k += 256) {
                float vv = (k < 512) ? ct[bi][k] : (k < 768) ? h1[b * 256 + k - 512]
                         : (k < 1024) ? c1[b * 256 + k - 768] : xw[b * 128 + k - 1024];
                pa += vv * Wpg[k];
            }
            pa = wave_red(pa);
            if ((threadIdx.x & 63) == 0) red[threadIdx.x >> 6] = pa;
            __syncthreads();
            if (threadIdx.x == 0)
                pgo[b] = sigf(red[0] + red[1] + red[2] + red[3] + bpg[0]);
            __syncthreads();
        }
    }
}

// ---------------------------------------------------------------------------
// K7: MFMA bf16 vocab GEMM + fused per-block softmax partials (replaces vs1).
// Block = 4 waves; wave w owns columns v0 + w*16 + (0..15), all 128 rows.
// After the K-loop each block computes per-row max and exp-sum over its 64
// cols: shfl_xor over the 16-lane n-groups, then LDS across q-groups/waves.
// Partials written [row][blk] (contiguous for the combiner in vs3).
// ---------------------------------------------------------------------------
__global__ __launch_bounds__(256) void k_gemm_mfma(
    const unsigned short* __restrict__ abf, const float* __restrict__ W2,
    const float* __restrict__ b2, float* __restrict__ fd,
    float* __restrict__ pM, float* __restrict__ pS)
{
    int tid = threadIdx.x;
    int w = tid >> 6, lane = tid & 63;
    int ln = lane & 15, q = lane >> 4;
    int vcol = blockIdx.x * 64 + w * 16 + ln;
    bool valid = vcol < Vv;
    const float* bptr = W2 + (size_t)(valid ? vcol : 0) * 256 + q * 8;
    const unsigned short* aptr = abf + ln * 256 + q * 8;

    f32x4 acc[8] = {};

    #pragma unroll
    for (int kk = 0; kk < 256; kk += 32) {
        float4 bv0 = *(const float4*)(bptr + kk);
        float4 bv1 = *(const float4*)(bptr + kk + 4);
        unsigned short bu[8] = {
            f2bf(bv0.x), f2bf(bv0.y), f2bf(bv0.z), f2bf(bv0.w),
            f2bf(bv1.x), f2bf(bv1.y), f2bf(bv1.z), f2bf(bv1.w)};
        bf16x8 bfr = __builtin_bit_cast(bf16x8, *(const bf16x8*)bu);
        #pragma unroll
        for (int mt = 0; mt < 8; mt++) {
            bf16x8 afr = *(const bf16x8*)(aptr + (size_t)mt * 16 * 256 + kk);
            acc[mt] = __builtin_amdgcn_mfma_f32_16x16x32_bf16(afr, bfr, acc[mt], 0, 0, 0);
        }
    }

    float bias = valid ? b2[vcol] : 0.f;

    __shared__ float Mw[4][128];
    __shared__ float Sw[4][128];
    __shared__ float Mrow[128];

    // store logits + per-(wave,row) max over 16 cols
    #pragma unroll
    for (int mt = 0; mt < 8; mt++) {
        #pragma unroll
        for (int r = 0; r < 4; r++) {
            int row = mt * 16 + q * 4 + r;
            float v = acc[mt][r] + bias;
            if (valid) fd[(size_t)row * VOo + vcol] = v;
            float mx = valid ? v : -3.4e38f;
            mx = fmaxf(mx, __shfl_xor(mx, 1));
            mx = fmaxf(mx, __shfl_xor(mx, 2));
            mx = fmaxf(mx, __shfl_xor(mx, 4));
            mx = fmaxf(mx, __shfl_xor(mx, 8));
            if (ln == 0) Mw[w][row] = mx;
        }
    }
    __syncthreads();
    if (tid < 128)
        Mrow[tid] = fmaxf(fmaxf(Mw[0][tid], Mw[1][tid]),
                          fmaxf(Mw[2][tid], Mw[3][tid]));
    __syncthreads();
    // exp-sum phase
    #pragma unroll
    for (int mt = 0; mt < 8; mt++) {
        #pragma unroll
        for (int r = 0; r < 4; r++) {
            int row = mt * 16 + q * 4 + r;
            float ev = valid ? __expf(acc[mt][r] + bias - Mrow[row]) : 0.f;
            ev += __shfl_xor(ev, 1);
            ev += __shfl_xor(ev, 2);
            ev += __shfl_xor(ev, 4);
            ev += __shfl_xor(ev, 8);
            if (ln == 0) Sw[w][row] = ev;
        }
    }
    __syncthreads();
    if (tid < 128) {
        pM[(size_t)tid * PSTR + blockIdx.x] = Mrow[tid];
        pS[(size_t)tid * PSTR + blockIdx.x] =
            Sw[0][tid] + Sw[1][tid] + Sw[2][tid] + Sw[3][tid];
    }
}

// ---------------------------------------------------------------------------
// K8: combine per-block partials (online merge) + normalize + p_gen scale
// + OOV tail. Each (b, quarter) block redundantly reduces the 782 partial
// (M,S) pairs for its row (6.3 KB, L2-hot).
// ---------------------------------------------------------------------------
__global__ __launch_bounds__(256) void k_vs3(
    const float* __restrict__ pM, const float* __restrict__ pS,
    const float* __restrict__ pgen, const float* __restrict__ extra,
    float* __restrict__ fd)
{
    int blk = blockIdx.x, b = blk >> 2, c = blk & 3;
    int tid = threadIdx.x;
    __shared__ float mred[4], sred[4];
    __shared__ float fMS[2];

    float m = -3.4e38f, s = 0.f;
    for (int i = tid; i < NBLK; i += 256) {
        float mi = pM[(size_t)b * PSTR + i];
        float si = pS[(size_t)b * PSTR + i];
        float M2 = fmaxf(m, mi);
        s = s * __expf(m - M2) + si * __expf(mi - M2);
        m = M2;
    }
    for (int off = 32; off; off >>= 1) {
        float mo = __shfl_down(m, off);
        float so = __shfl_down(s, off);
        float M2 = fmaxf(m, mo);
        s = s * __expf(m - M2) + so * __expf(mo - M2);
        m = M2;
    }
    if ((tid & 63) == 0) { mred[tid >> 6] = m; sred[tid >> 6] = s; }
    __syncthreads();
    if (tid == 0) {
        float M = mred[0], S = sred[0];
        for (int i = 1; i < 4; i++) {
            float M2 = fmaxf(M, mred[i]);
            S = S * __expf(M - M2) + sred[i] * __expf(mred[i] - M2);
            M = M2;
        }
        fMS[0] = M; fMS[1] = S;
    }
    __syncthreads();
    float M = fMS[0];
    float scale = pgen[b] / fMS[1];
    float* l = fd + (size_t)b * VOo + c * 12500;
    for (int v = tid; v < 12500; v += 256) l[v] = __expf(l[v] - M) * scale;
    if (c == 0 && tid < OOVn)
        fd[(size_t)b * VOo + Vv + tid] = extra[b * OOVn + tid];
}

// ---------------------------------------------------------------------------
// K9: pointer scatter-add
// ---------------------------------------------------------------------------
__global__ __launch_bounds__(256) void k_scatter(
    const int* __restrict__ ebev, const float* __restrict__ attn,
    const float* __restrict__ pgen, float* __restrict__ fd)
{
    int gid = blockIdx.x * 256 + threadIdx.x;
    if (gid >= Bb * TKk) return;
    int b = gid / TKk;
    float w = (1.f - pgen[b]) * attn[gid];
    atomicAdd(fd + (size_t)b * VOo + ebev[gid], w);
}

extern "C" void kernel_launch(void* const* d_in, const int* in_sizes, int n_in,
                              void* d_out, int out_size, void* d_ws, size_t ws_size,
                              hipStream_t stream)
{
    (void)in_sizes; (void)n_in; (void)out_size; (void)ws_size;

    const int*   y    = (const int*)d_in[0];
    const float* h0   = (const float*)d_in[1];
    const float* c0   = (const float*)d_in[2];
    const float* eo   = (const float*)d_in[3];
    const float* ef   = (const float*)d_in[4];
    const float* mask = (const float*)d_in[5];
    const float* ct1  = (const float*)d_in[6];
    const float* xz   = (const float*)d_in[7];
    const int*   ebev = (const int*)d_in[8];
    const float* cov  = (const float*)d_in[9];
    const float* emb  = (const float*)d_in[11];
    const float* Wx   = (const float*)d_in[12];
    const float* bx   = (const float*)d_in[13];
    const float* wih  = (const float*)d_in[14];
    const float* bih  = (const float*)d_in[15];
    const float* whh  = (const float*)d_in[16];
    const float* bhh  = (const float*)d_in[17];
    const float* Wp   = (const float*)d_in[18];
    const float* bp   = (const float*)d_in[19];
    const float* vw   = (const float*)d_in[20];
    const float* Wc   = (const float*)d_in[21];
    const float* Wpg  = (const float*)d_in[22];
    const float* bpg  = (const float*)d_in[23];
    const float* W1   = (const float*)d_in[24];
    const float* b1   = (const float*)d_in[25];
    const float* W2   = (const float*)d_in[26];
    const float* b2   = (const float*)d_in[27];

    float* out   = (float*)d_out;
    float* fd    = out;                              // [B, VO]
    float* h1o   = out + (size_t)Bb * VOo;           // [B, H]
    float* c1o   = h1o + (size_t)Bb * Hh;            // [B, H]
    float* cto   = c1o + (size_t)Bb * Hh;            // [B, N2]
    float* attno = cto + (size_t)Bb * N2n;           // [B, TK]
    float* pgo   = attno + (size_t)Bb * TKk;         // [B]
    float* covo  = pgo + Bb;                         // [B, TK]

    float* ws  = (float*)d_ws;
    float* xw  = ws;                                 // [B,128]
    float* dfw = xw + (size_t)Bb * EMB;              // [B,512]
    float* scw = dfw + (size_t)Bb * N2n;             // [B,400]
    float* prt = scw + (size_t)Bb * TKk;             // [B,4,512]
    float* pMw = prt + (size_t)Bb * 4 * N2n;         // [128, PSTR]
    float* pSw = pMw + (size_t)Bb * PSTR;            // [128, PSTR]
    unsigned short* abf = (unsigned short*)(pSw + (size_t)Bb * PSTR); // [B,256] bf16

    k_x<<<dim3(32, 32), 256, 0, stream>>>(y, ct1, emb, Wx, bx, xw);
    k_gates_lstm<<<dim3(256, 32), 256, 0, stream>>>(xw, h0, c0, wih, bih,
                                                    whh, bhh, h1o, c1o);
    k_dec_fea<<<dim3(128, 32), 256, 0, stream>>>(h1o, c1o, Wp, bp, dfw);
    k_scores<<<Bb * TKk / 4, 256, 0, stream>>>(ef, dfw, cov, Wc, vw, scw);
    k_attn_ctx<<<dim3(4, Bb), 512, 0, stream>>>(scw, mask, cov, eo, attno,
                                                covo, prt);
    k_out_ctred<<<dim3(64, 32), 256, 0, stream>>>(prt, h1o, c1o, xw, W1, b1,
                                                  Wpg, bpg, cto, pgo, abf);
    k_gemm_mfma<<<NBLK, 256, 0, stream>>>(abf, W2, b2, fd, pMw, pSw);
    k_vs3<<<512, 256, 0, stream>>>(pMw, pSw, pgo, xz, fd);
    k_scatter<<<(Bb * TKk + 255) / 256, 256, 0, stream>>>(ebev, attno, pgo, fd);
}